// Round 6
// baseline (441.110 us; speedup 1.0000x reference)
//
#include <hip/hip_runtime.h>
#include <hip/hip_fp16.h>

// Shapes (fixed by the reference setup_inputs)
#define NB 2
#define NH 16
#define NS 2048
#define ND 64

typedef __attribute__((ext_vector_type(8))) _Float16 half8;
typedef __attribute__((ext_vector_type(4))) _Float16 half4;
typedef __attribute__((ext_vector_type(4))) float float4v;

static constexpr int NE = NB * NH * NS * ND;     // 4,194,304 elems per tensor

// ---------------------------------------------------------------------------
// Kernel 1: RoPE(q), RoPE(k) -> fp16.
// ---------------------------------------------------------------------------
__global__ void rope_fp16_kernel(const float* __restrict__ q,
                                 const float* __restrict__ k,
                                 _Float16* __restrict__ qr,
                                 _Float16* __restrict__ kr) {
    int idx = blockIdx.x * blockDim.x + threadIdx.x;
    if (idx >= NE / 2) return;
    int i   = idx & 31;        // freq index
    int row = idx >> 5;        // (b*NH + h)*NS + s
    int s   = row & (NS - 1);

    float inv_freq = expf((float)i * -0.2878231366242710f);  // 10000^(-i/32)
    float ang = (float)s * inv_freq;
    float sn, cs;
    sincosf(ang, &sn, &cs);

    size_t base = (size_t)row * ND + 2 * i;
    float q0 = q[base], q1 = q[base + 1];
    float k0 = k[base], k1 = k[base + 1];
    qr[base]     = (_Float16)(q0 * cs - q1 * sn);
    qr[base + 1] = (_Float16)(q1 * cs + q0 * sn);
    kr[base]     = (_Float16)(k0 * cs - k1 * sn);
    kr[base + 1] = (_Float16)(k1 * cs + k0 * sn);
}

// ---------------------------------------------------------------------------
// Kernel 2: V [b,h,s,d] fp32 -> Vt [b,h,d,s] fp16.
// ---------------------------------------------------------------------------
__global__ void vtrans_fp16_kernel(const float* __restrict__ v,
                                   _Float16* __restrict__ vt) {
    int idx = blockIdx.x * blockDim.x + threadIdx.x;
    if (idx >= NE) return;
    int s  = idx & (NS - 1);
    int d  = (idx >> 11) & (ND - 1);
    int bh = idx >> 17;
    vt[idx] = (_Float16)v[((size_t)bh * NS + s) * ND + d];
}

// ---------------------------------------------------------------------------
// Kernel 3: bit-pack mask int32 [B,1,S,S] -> uint32 [B][S][S/32] via ballot.
// ---------------------------------------------------------------------------
__global__ void maskpack_kernel(const int* __restrict__ mask,
                                unsigned int* __restrict__ mp) {
    size_t idx = (size_t)blockIdx.x * 256 + threadIdx.x;   // over NB*NS*NS
    unsigned long long bal = __ballot(mask[idx] != 0);
    int l = threadIdx.x & 63;
    if (l == 0)       mp[idx >> 5] = (unsigned int)bal;
    else if (l == 32) mp[idx >> 5] = (unsigned int)(bal >> 32);
}

// ---------------------------------------------------------------------------
// Kernel A: invs prepass. WG = 4 waves = 64 q-rows; wave owns 16 complete
// rows over ALL 2048 cols -> register row sums, no cross-wave reduction,
// no score materialization. LDS: only the packed mask (16 KB). High
// occupancy (8 WG/CU), latency hidden by 8 waves/SIMD.
// ---------------------------------------------------------------------------
static constexpr int ATPB = 256;

__global__ __launch_bounds__(ATPB, 8)
void invs_kernel(const _Float16* __restrict__ qr,
                 const _Float16* __restrict__ kr,
                 const unsigned int* __restrict__ mp,
                 float* __restrict__ ginvs) {
    __shared__ unsigned int maskb[64 * 64];   // 16 KB

    int wgid = (blockIdx.x & 7) * 128 + (blockIdx.x >> 3);   // 1024 WGs, XCD swizzle
    int qt = wgid & 31;
    int bh = wgid >> 5;
    int b  = bh >> 4;
    int q0 = qt * 64;

    int tid = threadIdx.x;
    int w   = tid >> 6;
    int l   = tid & 63;
    int lm  = l & 15;
    int lp  = l >> 4;

    {
        const unsigned int* mrow = mp + ((size_t)b * NS + q0) * 64;
        for (int i = tid; i < 64 * 64; i += ATPB) maskb[i] = mrow[i];
    }
    const _Float16* qrow = qr + ((size_t)bh * NS + q0 + w * 16 + lm) * ND;
    half8 a0 = *(const half8*)(qrow + lp * 8);
    half8 a1 = *(const half8*)(qrow + 32 + lp * 8);
    const _Float16* kbase = kr + (size_t)bh * NS * ND;
    __syncthreads();

    float ps[4] = {0.f, 0.f, 0.f, 0.f};
#pragma unroll 4
    for (int kt = 0; kt < 128; ++kt) {
        int colbase = kt * 16;
        const _Float16* krow = kbase + (size_t)(colbase + lm) * ND;
        half8 b0 = *(const half8*)(krow + lp * 8);
        half8 b1 = *(const half8*)(krow + 32 + lp * 8);
        float4v acc = {0.f, 0.f, 0.f, 0.f};
        acc = __builtin_amdgcn_mfma_f32_16x16x32_f16(a0, b0, acc, 0, 0, 0);
        acc = __builtin_amdgcn_mfma_f32_16x16x32_f16(a1, b1, acc, 0, 0, 0);
        int word = (colbase + lm) >> 5;
        unsigned int bitm = 1u << ((colbase + lm) & 31);
#pragma unroll
        for (int r = 0; r < 4; ++r)
            ps[r] += (maskb[(w * 16 + lp * 4 + r) * 64 + word] & bitm)
                         ? __expf(acc[r] * 0.125f) : 0.f;
    }
#pragma unroll
    for (int off = 1; off < 16; off <<= 1) {
        ps[0] += __shfl_xor(ps[0], off);
        ps[1] += __shfl_xor(ps[1], off);
        ps[2] += __shfl_xor(ps[2], off);
        ps[3] += __shfl_xor(ps[3], off);
    }
    if (lm == 0) {
#pragma unroll
        for (int r = 0; r < 4; ++r) {
            int row = w * 16 + lp * 4 + r;
            float s = ps[r];
            ginvs[(size_t)bh * NS + q0 + row] = (s > 0.f) ? (1.f / s) : 0.f;
        }
    }
}

// ---------------------------------------------------------------------------
// Kernel B: streaming score + PV. One 16-row q-tile per WG, 8 waves,
// 512-col chunks. invs comes precomputed -> no full-row buffering; 29 KB
// LDS + 8 waves/SIMD VGPR cap -> 4 WG/CU, so staggered WGs keep the
// nt-store stream continuously fed while others compute.
// MFMA fragments (verified r1-r5): A lane: row=l&15, k=(l>>4)*8+[0..7];
// B same on B^T/Vt rows; C/D: col=l&15, row=(l>>4)*4+reg.
// ---------------------------------------------------------------------------
static constexpr int BTPB = 512;
static constexpr int CHW  = 512;             // chunk width (cols)
static constexpr int NCH  = NS / CHW;        // 4 chunks
static constexpr int EP   = CHW + 8;         // ebuf pitch in halfs

__global__ __launch_bounds__(BTPB, 8)
void score_pv_kernel(const _Float16* __restrict__ qr,
                     const _Float16* __restrict__ kr,
                     const _Float16* __restrict__ vt,
                     const unsigned int* __restrict__ mp,
                     const float* __restrict__ ginvs,
                     float* __restrict__ out,
                     float* __restrict__ score) {
    __shared__ _Float16     ebuf[16 * EP];        // 16,640 B
    __shared__ unsigned int maskb[16 * 64];       // 4,096 B
    __shared__ float        invs[16];
    __shared__ float        outb[2 * 16 * 64];    // 8,192 B

    int wgid = (blockIdx.x & 7) * 512 + (blockIdx.x >> 3);   // 4096 WGs, XCD swizzle
    int qt = wgid & 127;
    int bh = wgid >> 7;
    int b  = bh >> 4;
    int q0 = qt * 16;

    int tid = threadIdx.x;
    int w   = tid >> 6;
    int l   = tid & 63;
    int lm  = l & 15;
    int lp  = l >> 4;

    {
        const unsigned int* mrow = mp + ((size_t)b * NS + q0) * 64;
        for (int i = tid; i < 16 * 64; i += BTPB) maskb[i] = mrow[i];
        if (tid < 16) invs[tid] = ginvs[(size_t)bh * NS + q0 + tid];
    }
    const _Float16* qrow = qr + ((size_t)bh * NS + q0 + lm) * ND;
    half8 a0 = *(const half8*)(qrow + lp * 8);
    half8 a1 = *(const half8*)(qrow + 32 + lp * 8);
    const _Float16* kbase = kr + (size_t)bh * NS * ND;

    float4v oacc = {0.f, 0.f, 0.f, 0.f};
    int nt = w & 3, kh = w >> 2;              // PV ownership: d-block, k-half
    const _Float16* vbase = vt + ((size_t)bh * ND + nt * 16 + lm) * NS
                            + kh * (CHW / 2) + lp * 8;
    float* srow = score + ((size_t)bh * NS + q0) * NS;
    __syncthreads();

    for (int c = 0; c < NCH; ++c) {
        // ---- QK^T chunk: wave w computes cols [w*64, w*64+64) ----
#pragma unroll
        for (int t = 0; t < 4; ++t) {
            int lcolb   = w * 64 + t * 16;
            int colbase = c * CHW + lcolb;
            const _Float16* krow = kbase + (size_t)(colbase + lm) * ND;
            half8 b0 = *(const half8*)(krow + lp * 8);
            half8 b1 = *(const half8*)(krow + 32 + lp * 8);
            float4v acc = {0.f, 0.f, 0.f, 0.f};
            acc = __builtin_amdgcn_mfma_f32_16x16x32_f16(a0, b0, acc, 0, 0, 0);
            acc = __builtin_amdgcn_mfma_f32_16x16x32_f16(a1, b1, acc, 0, 0, 0);
            int word = (colbase + lm) >> 5;
            unsigned int bitm = 1u << ((colbase + lm) & 31);
            int lcol = lcolb + lm;
#pragma unroll
            for (int r = 0; r < 4; ++r) {
                int row = lp * 4 + r;
                float ev = (maskb[row * 64 + word] & bitm) ? __expf(acc[r] * 0.125f) : 0.f;
                ebuf[row * EP + lcol] = (_Float16)ev;   // unnormalized
            }
        }
        __syncthreads();

        // ---- score write: 16 x 512, normalized, nt-stores (L2-bypass) ----
#pragma unroll
        for (int it = 0; it < 4; ++it) {
            int i  = tid + it * BTPB;             // 0..2047 float4s
            int r  = i >> 7;
            int c4 = (i & 127) * 4;
            half4 hv = *(const half4*)(ebuf + r * EP + c4);
            float iv = invs[r];
            float4v f;
            f[0] = (float)hv[0] * iv;
            f[1] = (float)hv[1] * iv;
            f[2] = (float)hv[2] * iv;
            f[3] = (float)hv[3] * iv;
            __builtin_nontemporal_store(f, (float4v*)(srow + (size_t)r * NS + c * CHW + c4));
        }

        // ---- PV on unnormalized e: wave w does k-range [kh*256, +256) ----
#pragma unroll 2
        for (int ks = 0; ks < 8; ++ks) {
            half8 af = *(const half8*)(ebuf + lm * EP + kh * (CHW / 2) + ks * 32 + lp * 8);
            half8 bf = *(const half8*)(vbase + (size_t)c * CHW + ks * 32);
            oacc = __builtin_amdgcn_mfma_f32_16x16x32_f16(af, bf, oacc, 0, 0, 0);
        }
        __syncthreads();   // ebuf reuse for next chunk
    }

    // combine the two k-halves and write out
#pragma unroll
    for (int r = 0; r < 4; ++r)
        outb[kh * 1024 + (lp * 4 + r) * 64 + nt * 16 + lm] = oacc[r];
    __syncthreads();
    {
        float* orow = out + ((size_t)bh * NS + q0) * ND;
        for (int i = tid; i < 16 * 64; i += BTPB) {
            int r = i >> 6;
            __builtin_nontemporal_store((outb[i] + outb[1024 + i]) * invs[r], &orow[i]);
        }
    }
}

// ---------------------------------------------------------------------------
extern "C" void kernel_launch(void* const* d_in, const int* in_sizes, int n_in,
                              void* d_out, int out_size, void* d_ws, size_t ws_size,
                              hipStream_t stream) {
    const float* q    = (const float*)d_in[0];
    const float* k    = (const float*)d_in[1];
    const float* v    = (const float*)d_in[2];
    const int*   mask = (const int*)d_in[3];

    float* out   = (float*)d_out;            // [B,H,S,D]
    float* score = out + (size_t)NE;         // [B,H,S,S]

    _Float16* qrw = (_Float16*)d_ws;
    _Float16* krw = qrw + NE;
    _Float16* vtw = krw + NE;
    unsigned int* mp = (unsigned int*)(vtw + NE);             // 1 MB
    float* ginvs = (float*)(mp + (size_t)NB * NS * NS / 32);  // 256 KB

    rope_fp16_kernel<<<dim3((NE / 2 + 255) / 256), dim3(256), 0, stream>>>(q, k, qrw, krw);
    vtrans_fp16_kernel<<<dim3((NE + 255) / 256), dim3(256), 0, stream>>>(v, vtw);
    maskpack_kernel<<<dim3(NB * NS * NS / 256), dim3(256), 0, stream>>>(mask, mp);
    invs_kernel<<<dim3(NB * NH * (NS / 64)), dim3(ATPB), 0, stream>>>(qrw, krw, mp, ginvs);
    score_pv_kernel<<<dim3(NB * NH * (NS / 16)), dim3(BTPB), 0, stream>>>(
        qrw, krw, vtw, mp, ginvs, out, score);
}